// Round 1
// baseline (190.951 us; speedup 1.0000x reference)
//
#include <hip/hip_runtime.h>
#include <hip/hip_bf16.h>
#include <math.h>

#define B_SZ 512
#define D_SZ 2048
#define M_SZ 128
#define H_SZ 128
#define BCHUNK 128
#define NCHUNKS (B_SZ / BCHUNK)

typedef __attribute__((ext_vector_type(8))) short bf16x8;
typedef __attribute__((ext_vector_type(4))) float f32x4;
typedef __attribute__((ext_vector_type(4))) unsigned short us4;

__device__ __forceinline__ unsigned short f2bf(float f) {
    unsigned u = __builtin_bit_cast(unsigned, f);
    u += 0x7fffu + ((u >> 16) & 1u);   // round-to-nearest-even
    return (unsigned short)(u >> 16);
}

__global__ __launch_bounds__(256, 2) void nlm_kernel(
    const float* __restrict__ x,   // [B, D, M]
    const float* __restrict__ W1,  // [D, H, M]
    const float* __restrict__ b1,  // [D, H]
    const float* __restrict__ W2,  // [D, H]
    const float* __restrict__ b2,  // [D]
    float* __restrict__ out)       // [B, D]
{
    // LDS: rows of 128 bf16 = 256 B, XOR-swizzled (byte ^= (row&7)<<4) for
    // conflict-free ds_read_b128 fragment reads (G4 / T2).
    __shared__ __align__(16) unsigned short W1s[H_SZ * M_SZ]; // 32 KB
    __shared__ __align__(16) unsigned short Xs[BCHUNK * M_SZ]; // 32 KB
    __shared__ float w2s[H_SZ];
    __shared__ float b1s[H_SZ];
    __shared__ float red[2][BCHUNK];

    const int bid = blockIdx.x;
    // XCD-aware swizzle: XCD k gets d in [k*256, (k+1)*256) -> out-cacheline
    // (32 consecutive d) writes stay within one XCD's L2.
    const int d = (bid & 7) * 256 + (bid >> 3);

    const int tid = threadIdx.x;
    const int l    = tid & 63;
    const int w    = tid >> 6;
    const int wr   = w >> 1;       // wave row (B dim), 0..1
    const int wc   = w & 1;        // wave col (H dim), 0..1
    const int lrow = l & 15;
    const int lk   = l >> 4;
    const int swz  = (lrow & 7) << 4;

    // ---- stage W1[d] -> LDS bf16 (fully coalesced: 64 KB contiguous) ----
    const float* W1d = W1 + (size_t)d * (H_SZ * M_SZ);
    #pragma unroll
    for (int i = 0; i < 16; ++i) {
        int idx = tid + i * 256;          // float4 index 0..4095
        int r = idx >> 5, c4 = idx & 31;
        const float4 v = *(const float4*)(W1d + (r << 7) + (c4 << 2));
        us4 u; u.x = f2bf(v.x); u.y = f2bf(v.y); u.z = f2bf(v.z); u.w = f2bf(v.w);
        int byte = (r << 8) + (((c4 << 3)) ^ ((r & 7) << 4));
        *(us4*)((char*)W1s + byte) = u;
    }
    if (tid < H_SZ) {
        w2s[tid] = W2[(size_t)d * H_SZ + tid];
        b1s[tid] = b1[(size_t)d * H_SZ + tid];
    }
    const float b2v = b2[d];

    for (int c = 0; c < NCHUNKS; ++c) {
        const int b0 = c * BCHUNK;
        if (c) __syncthreads();   // protect Xs / red from overwrite

        // ---- stage X[b0:b0+128, d, :] -> LDS bf16 ----
        #pragma unroll
        for (int i = 0; i < 16; ++i) {
            int idx = tid + i * 256;
            int r = idx >> 5, c4 = idx & 31;
            const float4 v = *(const float4*)(x + ((size_t)(b0 + r) * D_SZ + d) * M_SZ + (c4 << 2));
            us4 u; u.x = f2bf(v.x); u.y = f2bf(v.y); u.z = f2bf(v.z); u.w = f2bf(v.w);
            int byte = (r << 8) + (((c4 << 3)) ^ ((r & 7) << 4));
            *(us4*)((char*)Xs + byte) = u;
        }
        __syncthreads();

        // ---- MFMA: h[128x128] = X[128x128] * W1^T, K = M = 128 ----
        f32x4 acc[4][4];
        #pragma unroll
        for (int m = 0; m < 4; ++m)
            #pragma unroll
            for (int n = 0; n < 4; ++n)
                acc[m][n] = (f32x4){0.f, 0.f, 0.f, 0.f};

        #pragma unroll
        for (int k = 0; k < 4; ++k) {
            const int colb = (k << 6) + (lk << 4);   // byte offset of 8 bf16 in k
            bf16x8 a[4], bb[4];
            #pragma unroll
            for (int m = 0; m < 4; ++m) {
                int row = wr * 64 + m * 16 + lrow;   // B row
                a[m] = *(const bf16x8*)((const char*)Xs + (row << 8) + (colb ^ swz));
            }
            #pragma unroll
            for (int n = 0; n < 4; ++n) {
                int row = wc * 64 + n * 16 + lrow;   // H row of W1 (B-operand col)
                bb[n] = *(const bf16x8*)((const char*)W1s + (row << 8) + (colb ^ swz));
            }
            #pragma unroll
            for (int m = 0; m < 4; ++m)
                #pragma unroll
                for (int n = 0; n < 4; ++n)
                    acc[m][n] = __builtin_amdgcn_mfma_f32_16x16x32_bf16(a[m], bb[n], acc[m][n], 0, 0, 0);
        }

        // ---- epilogue: +b1, exact gelu, dot with W2, reduce over H ----
        // C/D layout: col = lane&15, row = (lane>>4)*4 + reg  [m89-verified]
        float p[4][4];
        #pragma unroll
        for (int m = 0; m < 4; ++m)
            #pragma unroll
            for (int r = 0; r < 4; ++r)
                p[m][r] = 0.f;

        #pragma unroll
        for (int n = 0; n < 4; ++n) {
            const int cn = wc * 64 + n * 16 + lrow;   // h' index
            const float w2v = w2s[cn];
            const float b1v = b1s[cn];
            #pragma unroll
            for (int m = 0; m < 4; ++m)
                #pragma unroll
                for (int r = 0; r < 4; ++r) {
                    float h = acc[m][n][r] + b1v;
                    float g = 0.5f * h * (1.0f + erff(h * 0.70710678118654752f));
                    p[m][r] += g * w2v;
                }
        }

        // reduce over the 16 lanes of the column group (cols n*16 + lrow)
        #pragma unroll
        for (int off = 1; off < 16; off <<= 1)
            #pragma unroll
            for (int m = 0; m < 4; ++m)
                #pragma unroll
                for (int r = 0; r < 4; ++r)
                    p[m][r] += __shfl_xor(p[m][r], off, 64);

        if (lrow == 0) {
            #pragma unroll
            for (int m = 0; m < 4; ++m)
                #pragma unroll
                for (int r = 0; r < 4; ++r)
                    red[wc][wr * 64 + m * 16 + lk * 4 + r] = p[m][r];
        }
        __syncthreads();

        if (tid < BCHUNK) {
            float v = red[0][tid] + red[1][tid] + b2v;
            out[(size_t)(b0 + tid) * D_SZ + d] = v;
        }
    }
}

extern "C" void kernel_launch(void* const* d_in, const int* in_sizes, int n_in,
                              void* d_out, int out_size, void* d_ws, size_t ws_size,
                              hipStream_t stream) {
    const float* x  = (const float*)d_in[0];
    const float* W1 = (const float*)d_in[1];
    const float* b1 = (const float*)d_in[2];
    const float* W2 = (const float*)d_in[3];
    const float* b2 = (const float*)d_in[4];
    float* out = (float*)d_out;

    hipLaunchKernelGGL(nlm_kernel, dim3(D_SZ), dim3(256), 0, stream,
                       x, W1, b1, W2, b2, out);
}

// Round 2
// 146.827 us; speedup vs baseline: 1.3005x; 1.3005x over previous
//
#include <hip/hip_runtime.h>
#include <hip/hip_bf16.h>
#include <math.h>

#define B_SZ 512
#define D_SZ 2048
#define M_SZ 128
#define H_SZ 128
#define BCHUNK 64
#define NCHUNKS (B_SZ / BCHUNK)

typedef __attribute__((ext_vector_type(8))) short bf16x8;
typedef __attribute__((ext_vector_type(4))) float f32x4;
typedef __attribute__((ext_vector_type(4))) unsigned short us4;

__device__ __forceinline__ unsigned short f2bf(float f) {
    unsigned u = __builtin_bit_cast(unsigned, f);
    u += 0x7fffu + ((u >> 16) & 1u);   // round-to-nearest-even
    return (unsigned short)(u >> 16);
}

__global__ __launch_bounds__(256, 3) void nlm_kernel(
    const float* __restrict__ x,   // [B, D, M]
    const float* __restrict__ W1,  // [D, H, M]
    const float* __restrict__ b1,  // [D, H]
    const float* __restrict__ W2,  // [D, H]
    const float* __restrict__ b2,  // [D]
    float* __restrict__ out)       // [B, D]
{
    // LDS rows = 128 bf16 = 256 B, XOR-swizzled (byte ^= (row&7)<<4) for
    // conflict-free ds_read_b128 fragment reads (G4 / T2).
    __shared__ __align__(16) unsigned short W1s[H_SZ * M_SZ];   // 32 KB
    __shared__ __align__(16) unsigned short Xs[BCHUNK * M_SZ];  // 16 KB
    __shared__ float w2s[H_SZ];
    __shared__ float b1s[H_SZ];
    __shared__ float red[2][BCHUNK];

    const int bid = blockIdx.x;
    // XCD-aware swizzle: XCD k owns d in [k*256,(k+1)*256) -> the 16 d's of
    // each out cacheline come from the same XCD's L2 (write combining).
    const int d = (bid & 7) * 256 + (bid >> 3);

    const int tid  = threadIdx.x;
    const int l    = tid & 63;
    const int w    = tid >> 6;
    const int wr   = w >> 1;       // wave row (B dim), 0..1 -> 32 rows each
    const int wc   = w & 1;        // wave col (H dim), 0..1 -> 64 cols each
    const int lrow = l & 15;
    const int lk   = l >> 4;
    const int swz  = (lrow & 7) << 4;

    // ---- stage W1[d] -> LDS bf16 (64 KB contiguous, fully coalesced) ----
    const float* W1d = W1 + (size_t)d * (H_SZ * M_SZ);
    #pragma unroll
    for (int i = 0; i < 16; ++i) {
        int idx = tid + i * 256;          // float4 index 0..4095
        int r = idx >> 5, c4 = idx & 31;
        const float4 v = *(const float4*)(W1d + (r << 7) + (c4 << 2));
        us4 u; u.x = f2bf(v.x); u.y = f2bf(v.y); u.z = f2bf(v.z); u.w = f2bf(v.w);
        int byte = (r << 8) + ((c4 << 3) ^ ((r & 7) << 4));
        *(us4*)((char*)W1s + byte) = u;
    }
    if (tid < H_SZ) {
        w2s[tid] = W2[(size_t)d * H_SZ + tid];
        b1s[tid] = b1[(size_t)d * H_SZ + tid];
    }
    const float b2v = b2[d];

    // ---- issue chunk-0 X loads into registers (T14 issue-early) ----
    const int xr_row = tid >> 5;          // base row within chunk (0..7)
    const int xr_c4  = tid & 31;          // float4 column
    float4 xr[8];
    #pragma unroll
    for (int i = 0; i < 8; ++i)
        xr[i] = *(const float4*)(x + ((size_t)(xr_row + i * 8) * D_SZ + d) * M_SZ + (xr_c4 << 2));

    for (int c = 0; c < NCHUNKS; ++c) {
        // ---- consume staged regs: convert + write Xs ----
        #pragma unroll
        for (int i = 0; i < 8; ++i) {
            int r = xr_row + i * 8;
            us4 u; u.x = f2bf(xr[i].x); u.y = f2bf(xr[i].y);
                   u.z = f2bf(xr[i].z); u.w = f2bf(xr[i].w);
            int byte = (r << 8) + ((xr_c4 << 3) ^ ((r & 7) << 4));
            *(us4*)((char*)Xs + byte) = u;
        }
        __syncthreads();   // Xs (and, on c==0, W1s/w2s/b1s) ready

        // ---- issue next chunk's X loads; they stay in flight across compute ----
        if (c + 1 < NCHUNKS) {
            const size_t b0n = (size_t)(c + 1) * BCHUNK;
            #pragma unroll
            for (int i = 0; i < 8; ++i)
                xr[i] = *(const float4*)(x + ((b0n + xr_row + i * 8) * D_SZ + d) * M_SZ + (xr_c4 << 2));
        }

        // ---- MFMA: h[64x128] = X[64x128] * W1^T, K = M = 128 ----
        f32x4 acc[2][4];
        #pragma unroll
        for (int m = 0; m < 2; ++m)
            #pragma unroll
            for (int n = 0; n < 4; ++n)
                acc[m][n] = (f32x4){0.f, 0.f, 0.f, 0.f};

        #pragma unroll
        for (int k = 0; k < 4; ++k) {
            const int colb = (k << 6) + (lk << 4);   // byte offset of 8 bf16
            bf16x8 a[2], bb[4];
            #pragma unroll
            for (int m = 0; m < 2; ++m) {
                int row = wr * 32 + m * 16 + lrow;   // B row
                a[m] = *(const bf16x8*)((const char*)Xs + (row << 8) + (colb ^ swz));
            }
            #pragma unroll
            for (int n = 0; n < 4; ++n) {
                int row = wc * 64 + n * 16 + lrow;   // H row of W1
                bb[n] = *(const bf16x8*)((const char*)W1s + (row << 8) + (colb ^ swz));
            }
            #pragma unroll
            for (int m = 0; m < 2; ++m)
                #pragma unroll
                for (int n = 0; n < 4; ++n)
                    acc[m][n] = __builtin_amdgcn_mfma_f32_16x16x32_bf16(a[m], bb[n], acc[m][n], 0, 0, 0);
        }

        // ---- epilogue: +b1, exact gelu, dot W2, reduce over H ----
        // C/D layout: col = lane&15, row = (lane>>4)*4 + reg  [m89]
        float p[2][4];
        #pragma unroll
        for (int m = 0; m < 2; ++m)
            #pragma unroll
            for (int r = 0; r < 4; ++r)
                p[m][r] = 0.f;

        #pragma unroll
        for (int n = 0; n < 4; ++n) {
            const int cn = wc * 64 + n * 16 + lrow;
            const float w2v = w2s[cn];
            const float b1v = b1s[cn];
            #pragma unroll
            for (int m = 0; m < 2; ++m)
                #pragma unroll
                for (int r = 0; r < 4; ++r) {
                    float h = acc[m][n][r] + b1v;
                    float g = 0.5f * h * (1.0f + erff(h * 0.70710678118654752f));
                    p[m][r] += g * w2v;
                }
        }

        // reduce over the 16 lanes of the column group
        #pragma unroll
        for (int off = 1; off < 16; off <<= 1)
            #pragma unroll
            for (int m = 0; m < 2; ++m)
                #pragma unroll
                for (int r = 0; r < 4; ++r)
                    p[m][r] += __shfl_xor(p[m][r], off, 64);

        if (lrow == 0) {
            #pragma unroll
            for (int m = 0; m < 2; ++m)
                #pragma unroll
                for (int r = 0; r < 4; ++r)
                    red[wc][wr * 32 + m * 16 + lk * 4 + r] = p[m][r];
        }
        __syncthreads();   // red ready; Xs reads complete (safe to overwrite)

        if (tid < BCHUNK) {
            float v = red[0][tid] + red[1][tid] + b2v;
            out[(size_t)(c * BCHUNK + tid) * D_SZ + d] = v;
        }
    }
}

extern "C" void kernel_launch(void* const* d_in, const int* in_sizes, int n_in,
                              void* d_out, int out_size, void* d_ws, size_t ws_size,
                              hipStream_t stream) {
    const float* x  = (const float*)d_in[0];
    const float* W1 = (const float*)d_in[1];
    const float* b1 = (const float*)d_in[2];
    const float* W2 = (const float*)d_in[3];
    const float* b2 = (const float*)d_in[4];
    float* out = (float*)d_out;

    hipLaunchKernelGGL(nlm_kernel, dim3(D_SZ), dim3(256), 0, stream,
                       x, W1, b1, W2, b2, out);
}